// Round 14
// baseline (70.613 us; speedup 1.0000x reference)
//
#include <hip/hip_runtime.h>
#include <math.h>

#define HW 256
#define MINNORM 1.17549435e-38f   // 2^-126, f32 min normal

// np ref semantics (verified R4..R13): XLA-CPU f32, FTZ/DAZ, pow underflow at
// j=42 -> support lives in [0,41].
// HARD-WON:
//  R10: flush+renormalize must happen at ref's exact points/scales each step.
//  R11: no cancellation forms for output p_z.
//  R7/R12/R13: issue-count, scheduling, and chain-round halving all NEUTRAL —
//   the limiter is per-step readlane->SGPR->VALU hazard stalls at 1 wave/SIMD.
// R14: readlane-free reduction. Layout: 16 lanes x 3 slots per batch
//  (lane c holds j = c+16s), 4 batches per wave (row r = batch 4*blk+r).
//  Row sum = all-lane rotation butterfly: quad_perm x2 + row_ror:4/8
//  (ctrl < 0x130: retained on CDNA; R5's fault was 0x142/0x143).
//  Per-row norm lands broadcast in-row; dead rows coast at exact 0.

struct InvTbl { float v[HW]; };
static constexpr InvTbl make_inv() {
    InvTbl t{};
    for (int i = 0; i < HW; ++i) t.v[i] = 1.0f / (float)(HW - i);  // CR 1/den
    return t;
}
__constant__ InvTbl INVD = make_inv();

template <int CTRL>
__device__ __forceinline__ float dpp_add(float x) {
    int s = __builtin_amdgcn_update_dpp(0, __builtin_bit_cast(int, x),
                                        CTRL, 0xf, 0xf, true);
    return x + __builtin_bit_cast(float, s);
}

// 16-lane row sum, broadcast to ALL lanes of the row (no readlane):
// quad pair-sums, quad sums, then cross-quad rotations.
__device__ __forceinline__ float rowsum_bcast(float x) {
    x = dpp_add<0xB1>(x);    // quad_perm [1,0,3,2]
    x = dpp_add<0x4E>(x);    // quad_perm [2,3,0,1]
    x = dpp_add<0x124>(x);   // row_ror:4
    x = dpp_add<0x128>(x);   // row_ror:8
    return x;
}
__device__ __forceinline__ void rowsum_bcast2(float a, float z,
                                              float& ra, float& rz) {
    a = dpp_add<0xB1>(a);   z = dpp_add<0xB1>(z);
    a = dpp_add<0x4E>(a);   z = dpp_add<0x4E>(z);
    a = dpp_add<0x124>(a);  z = dpp_add<0x124>(z);
    a = dpp_add<0x128>(a);  z = dpp_add<0x128>(z);
    ra = a; rz = z;
}

__global__ void __launch_bounds__(64)
spair_count_kl(const float* __restrict__ z_pres,
               const float* __restrict__ z_prob,
               float* __restrict__ out) {
    // f32 denorm = flush in+out (FP_DENORM[1:0]=0), matching XLA FTZ (= R9).
    float tok;
    asm volatile("s_setreg_imm32_b32 hwreg(HW_REG_MODE, 4, 2), 0\n\t"
                 "v_mov_b32 %0, 0" : "=v"(tok));

    const int lane = threadIdx.x;       // 0..63
    const int c = lane & 15;            // column within row
    const int b = blockIdx.x * 4 + (lane >> 4);   // batch for this row

    // ---- cd0 init per slot (element-wise identical to R4..R13) ----
    const float e2f = (float)exp(2.0);
    const float pf  = (float)(1.0 / ((double)e2f + 1.0));
    const double pd = (double)pf;
    const double l2p = log2(pd);
    float cd[3], jf[3];
#pragma unroll
    for (int s = 0; s < 3; ++s) {
        const int j = c + 16 * s;       // j in [0,47]
        jf[s] = (float)j;
        float v = 0.0f;
        if (j <= 41) {
            const double powj = exp2((double)j * l2p);
            float w = (float)((1.0 - pd) * powj);
            v = (w < MINNORM) ? 0.0f : w;   // j=41 survives (1.006*2^-126)
        }
        cd[s] = v;
    }
    {
        const float part = (cd[0] + cd[1]) + cd[2];
        const float rsum = rowsum_bcast(part);
#pragma unroll
        for (int s = 0; s < 3; ++s) cd[s] = cd[s] / rsum + tok;
    }
    float csf = tok;

    const float* presb = z_pres + (size_t)b * HW;
    const float* probb = z_prob + (size_t)b * HW;
    float* outb = out + (size_t)b * HW;

    bool dead = false;

#pragma unroll 1
    for (int k = 0; k < 4; ++k) {
        float pres_q[4], prob_q[4];
#pragma unroll
        for (int q = 0; q < 4; ++q) {
            pres_q[q] = presb[k * 64 + q * 16 + c];
            prob_q[q] = probb[k * 64 + q * 16 + c];
        }
        // per-phase sample masks; row-local 16-bit views
        unsigned int rm[4];
#pragma unroll
        for (int q = 0; q < 4; ++q) {
            const unsigned long long m = __ballot(rintf(pres_q[q]) != 0.0f);
            rm[q] = (unsigned int)(m >> (lane & 48));
        }
        float pzq[4] = {0.0f, 0.0f, 0.0f, 0.0f};

        if (!dead) {
#pragma unroll 1
            for (int q = 0; q < 4; ++q) {
                float lastA = 1.0f;
#pragma unroll
                for (int cc = 0; cc < 16; ++cc) {
                    const int i = k * 64 + q * 16 + cc;
                    const float fden = (float)(HW - i);   // exact int
                    const float inv = INVD.v[i];          // uniform CR 1/den
                    const unsigned int bit = (rm[q] >> cc) & 1u;
                    const bool s1 = bit != 0u;

                    float pm[3], p1v[3];
#pragma unroll
                    for (int s = 0; s < 3; ++s) {
                        const float d = jf[s] - csf;          // exact int
                        const float pg0 = fmaxf(d, 0.0f) * inv;
                        const float pg = (d >= fden) ? 1.0f : pg0; // exact 1
                        const float mult = s1 ? pg : (1.0f - pg);  // exact 0/1
                        pm[s]  = cd[s] * mult;   // HW-FTZ (ref flush point)
                        p1v[s] = cd[s] * pg;     // HW-FTZ (p_z terms)
                    }
                    const float apart = (pm[0] + pm[1]) + pm[2];
                    const float zpart = (p1v[0] + p1v[1]) + p1v[2];
                    float atot, ztot;
                    rowsum_bcast2(apart, zpart, atot, ztot); // per-row sums

                    const float norm = fmaxf(atot, 1e-6f);   // clip(sum,1e-6,∞)
                    const float invn = __builtin_amdgcn_rcpf(norm);
#pragma unroll
                    for (int s = 0; s < 3; ++s) cd[s] = pm[s] * invn; // HW-FTZ
                    csf += (float)bit;

                    pzq[q] = (cc == c) ? ztot : pzq[q];      // capture step pz
                    lastA = atot;
                }
                // all four rows dead? (norm presum exactly 0 is absorbing)
                if (__ballot(lastA != 0.0f) == 0ULL) { dead = true; break; }
            }
        }

        // KL epilogue: lane (row,c) owns steps q*16+c of its batch
#pragma unroll
        for (int q = 0; q < 4; ++q) {
            const float prob = prob_q[q];
            const float pz = pzq[q];   // 0 on dead steps = ref's closed form
            const float kl = prob * (logf(prob + 1e-9f) - logf(pz + 1e-9f))
                           + (1.0f - prob) * (logf((1.0f - prob) + 1e-9f)
                                            - logf((1.0f - pz) + 1e-9f));
            outb[k * 64 + q * 16 + c] = kl;
        }
    }
}

extern "C" void kernel_launch(void* const* d_in, const int* in_sizes, int n_in,
                              void* d_out, int out_size, void* d_ws, size_t ws_size,
                              hipStream_t stream) {
    const float* z_pres = (const float*)d_in[0];      // setup_inputs order
    const float* z_prob = (const float*)d_in[1];
    float* out = (float*)d_out;
    const int nbatch = in_sizes[0] / HW;              // 1024
    spair_count_kl<<<dim3(nbatch / 4), dim3(64), 0, stream>>>(z_pres, z_prob, out);
}